// Round 8
// baseline (450.353 us; speedup 1.0000x reference)
//
#include <hip/hip_runtime.h>
#include <hip/hip_cooperative_groups.h>
namespace cg = cooperative_groups;

// N=100000 nodes, E=1600000 edges, D=64.
#define D_FEAT 64
#define TILE 4096            // edges per hist/partition tile -> ntiles = 391
#define MAXB 512             // max buckets (nb = ceil(N/256) = 391)

// Edge packing: (local_row << 24) | col   (col < 2^24, local_row < 256)
// hist_t / base_local layout: [bucket * ntiles + tile]

__device__ inline unsigned short f2bf(float f) {
    unsigned u = __float_as_uint(f);
    u += 0x7FFFu + ((u >> 16) & 1u);   // RNE
    return (unsigned short)(u >> 16);
}
__device__ inline float bf2f(unsigned short u) {
    return __uint_as_float(((unsigned)u) << 16);
}

// One cooperative kernel: hist -> per-bucket bases -> bucket_off scan ->
// partition -> per-bucket CSR -> fp32->bf16 feature copy.
// 391 blocks x 256 thr, LDS 3KB, __launch_bounds__(256,2) guarantees 2 blocks/CU
// co-residency (391 <= 512).
__global__ __launch_bounds__(256, 2)
void preprocess_coop(const float* __restrict__ feat,
                     const int* __restrict__ row, const int* __restrict__ col,
                     int* __restrict__ hist_t, int* __restrict__ base_local,
                     int* __restrict__ bucket_total, int* __restrict__ bucket_off,
                     int* __restrict__ offsets, int* __restrict__ binned,
                     int* __restrict__ sorted_col, unsigned short* __restrict__ feat_bf,
                     int n_nodes, int n_edges, int nb, int ntiles) {
    cg::grid_group grid = cg::this_grid();
    __shared__ int smem[768];
    const int gb = blockIdx.x;
    const int t = threadIdx.x;

    // ---- P1: per-tile bucket histogram ----
    if (gb < ntiles) {
        for (int i = t; i < MAXB; i += 256) smem[i] = 0;
        __syncthreads();
        int e0 = gb * TILE, e1 = min(e0 + TILE, n_edges);
        for (int e = e0 + t; e < e1; e += 256)
            atomicAdd(&smem[row[e] >> 8], 1);
        __syncthreads();
        for (int i = t; i < nb; i += 256)
            hist_t[(size_t)i * ntiles + gb] = smem[i];
    }
    grid.sync();

    // ---- P2: per-bucket exclusive scan over tiles (block gb = bucket gb) ----
    if (gb < nb) {
        const int* hp = hist_t + (size_t)gb * ntiles;
        int j0 = 2 * t, j1 = 2 * t + 1;
        int v0 = (j0 < ntiles) ? hp[j0] : 0;
        int v1 = (j1 < ntiles) ? hp[j1] : 0;
        int ps = v0 + v1;
        smem[t] = ps;
        __syncthreads();
        for (int o = 1; o < 256; o <<= 1) {
            int x = (t >= o) ? smem[t - o] : 0;
            __syncthreads();
            smem[t] += x;
            __syncthreads();
        }
        int excl = smem[t] - ps;
        if (j0 < ntiles) base_local[(size_t)gb * ntiles + j0] = excl;
        if (j1 < ntiles) base_local[(size_t)gb * ntiles + j1] = excl + v0;
        if (t == 255) bucket_total[gb] = smem[255];
    }
    grid.sync();

    // ---- P3: exclusive scan of bucket totals (block 0 only) ----
    if (gb == 0) {
        int j0 = 2 * t, j1 = 2 * t + 1;
        int v0 = (j0 < nb) ? bucket_total[j0] : 0;
        int v1 = (j1 < nb) ? bucket_total[j1] : 0;
        int ps = v0 + v1;
        smem[t] = ps;
        __syncthreads();
        for (int o = 1; o < 256; o <<= 1) {
            int x = (t >= o) ? smem[t - o] : 0;
            __syncthreads();
            smem[t] += x;
            __syncthreads();
        }
        int excl = smem[t] - ps;
        if (j0 < nb) bucket_off[j0] = excl;
        if (j1 < nb) bucket_off[j1] = excl + v0;
        if (t == 0) {
            bucket_off[nb] = n_edges;
            offsets[n_nodes] = n_edges;
        }
    }
    grid.sync();

    // ---- P4: partition tile gb into bucket regions (LDS cursors) ----
    if (gb < ntiles) {
        for (int i = t; i < nb; i += 256)
            smem[i] = bucket_off[i] + base_local[(size_t)i * ntiles + gb];
        __syncthreads();
        int e0 = gb * TILE, e1 = min(e0 + TILE, n_edges);
        for (int e = e0 + t; e < e1; e += 256) {
            int r = row[e];
            int pos = atomicAdd(&smem[r >> 8], 1);
            binned[pos] = ((r & 255) << 24) | col[e];
        }
    }
    grid.sync();

    // ---- P5: per-bucket exact CSR (block gb = bucket gb) ----
    if (gb < nb) {
        int* cnt = smem;
        int* sc = smem + 256;
        int* cur = smem + 512;
        int r0 = gb << 8;
        int start = bucket_off[gb], end = bucket_off[gb + 1];
        cnt[t] = 0;
        __syncthreads();
        for (int i = start + t; i < end; i += 256)
            atomicAdd(&cnt[((unsigned)binned[i]) >> 24], 1);
        __syncthreads();
        int v = cnt[t];
        sc[t] = v;
        __syncthreads();
        for (int o = 1; o < 256; o <<= 1) {
            int x = (t >= o) ? sc[t - o] : 0;
            __syncthreads();
            sc[t] += x;
            __syncthreads();
        }
        int excl = sc[t] - v;
        cur[t] = excl;
        int r = r0 + t;
        if (r < n_nodes) offsets[r] = start + excl;
        __syncthreads();
        for (int i = start + t; i < end; i += 256) {
            int pk = binned[i];
            int lr = ((unsigned)pk) >> 24;
            int pos = start + atomicAdd(&cur[lr], 1);
            sorted_col[pos] = pk & 0xFFFFFF;
        }
    }
    grid.sync();

    // ---- P6: fp32 -> bf16 feature copy (overlays binned region; all
    //          binned/hist_t/base_local consumers are done) ----
    {
        int n4 = n_nodes * D_FEAT / 4;
        int stride = gridDim.x * 256;
        for (int i = gb * 256 + t; i < n4; i += stride) {
            float4 f = reinterpret_cast<const float4*>(feat)[i];
            ushort4 u;
            u.x = f2bf(f.x); u.y = f2bf(f.y); u.z = f2bf(f.z); u.w = f2bf(f.w);
            reinterpret_cast<ushort4*>(feat_bf)[i] = u;
        }
    }
}

// ---------------- one wave per row; bf16 gather ------------------------
__global__ __launch_bounds__(256)
void aggregate_kernel(const float* __restrict__ feat,
                      const unsigned short* __restrict__ feat_bf,
                      const int* __restrict__ offsets,
                      const int* __restrict__ sorted_col,
                      float* __restrict__ out, int n_nodes) {
    int wave = (blockIdx.x * blockDim.x + threadIdx.x) >> 6;
    int lane = threadIdx.x & 63;
    if (wave >= n_nodes) return;
    int start = offsets[wave];
    int end = offsets[wave + 1];
    int deg = end - start;
    int q = lane >> 4;     // 4 edge-groups
    int sub = lane & 15;   // ushort4 slot within the 64-dim row

    float4 acc0 = make_float4(0.f, 0.f, 0.f, 0.f);
    float4 acc1 = make_float4(0.f, 0.f, 0.f, 0.f);

    for (int base = 0; base < deg; base += 64) {
        int idx = base + lane;
        int colv = (idx < deg) ? sorted_col[start + idx] : 0;
        int m = min(64, deg - base);
        for (int i = 0; i < m; i += 8) {
            int j0 = i + q;
            int j1 = i + 4 + q;
            int c0 = __shfl(colv, j0, 64);
            int c1 = __shfl(colv, j1, 64);
            if (j0 < m) {
                ushort4 v = *reinterpret_cast<const ushort4*>(
                    feat_bf + (size_t)c0 * D_FEAT + sub * 4);
                acc0.x += bf2f(v.x); acc0.y += bf2f(v.y);
                acc0.z += bf2f(v.z); acc0.w += bf2f(v.w);
            }
            if (j1 < m) {
                ushort4 v = *reinterpret_cast<const ushort4*>(
                    feat_bf + (size_t)c1 * D_FEAT + sub * 4);
                acc1.x += bf2f(v.x); acc1.y += bf2f(v.y);
                acc1.z += bf2f(v.z); acc1.w += bf2f(v.w);
            }
        }
    }
    acc0.x += acc1.x; acc0.y += acc1.y; acc0.z += acc1.z; acc0.w += acc1.w;
    acc0.x += __shfl_xor(acc0.x, 16, 64);
    acc0.y += __shfl_xor(acc0.y, 16, 64);
    acc0.z += __shfl_xor(acc0.z, 16, 64);
    acc0.w += __shfl_xor(acc0.w, 16, 64);
    acc0.x += __shfl_xor(acc0.x, 32, 64);
    acc0.y += __shfl_xor(acc0.y, 32, 64);
    acc0.z += __shfl_xor(acc0.z, 32, 64);
    acc0.w += __shfl_xor(acc0.w, 32, 64);
    if (q == 0) {
        float inv = 1.0f / fmaxf((float)deg, 1.0f);
        size_t off = (size_t)wave * D_FEAT + sub * 4;
        const float4 f = *reinterpret_cast<const float4*>(feat + off);
        float4 o;
        o.x = f.x + acc0.x * inv;
        o.y = f.y + acc0.y * inv;
        o.z = f.z + acc0.z * inv;
        o.w = f.w + acc0.w * inv;
        *reinterpret_cast<float4*>(out + off) = o;
    }
}

extern "C" void kernel_launch(void* const* d_in, const int* in_sizes, int n_in,
                              void* d_out, int out_size, void* d_ws, size_t ws_size,
                              hipStream_t stream) {
    const float* feat = (const float*)d_in[0];
    const int* row = (const int*)d_in[1];
    const int* col = (const int*)d_in[2];
    float* out = (float*)d_out;

    int n_nodes = in_sizes[0] / D_FEAT;
    int n_edges = in_sizes[1];
    int nb = (n_nodes + 255) >> 8;                  // 391
    int ntiles = (n_edges + TILE - 1) / TILE;       // 391
    int grid = (nb > ntiles) ? nb : ntiles;

    // Workspace layout. Overlay: feat_bf (written in P6, after all consumers
    // of binned/hist_t/base_local finish) shares the first OV bytes.
    char* ws = (char*)d_ws;
    size_t sort_bytes = (size_t)n_edges * 4                 // binned
                      + (size_t)nb * ntiles * 4             // hist_t
                      + (size_t)nb * ntiles * 4;            // base_local
    size_t bf_bytes = (size_t)n_nodes * D_FEAT * 2;         // 12.8 MB
    size_t OV = (sort_bytes > bf_bytes ? sort_bytes : bf_bytes);
    OV = (OV + 15) & ~(size_t)15;

    unsigned short* feat_bf = (unsigned short*)ws;
    int* binned     = (int*)ws;
    int* hist_t     = (int*)(ws + (size_t)n_edges * 4);
    int* base_local = hist_t + (size_t)nb * ntiles;

    size_t p = OV;
    int* sorted_col   = (int*)(ws + p); p += (size_t)n_edges * 4;
    int* offsets      = (int*)(ws + p); p += (size_t)(n_nodes + 1) * 4;
    int* bucket_off   = (int*)(ws + p); p += (size_t)(nb + 1) * 4;
    int* bucket_total = (int*)(ws + p); p += (size_t)nb * 4;

    void* args[] = {
        (void*)&feat, (void*)&row, (void*)&col,
        (void*)&hist_t, (void*)&base_local, (void*)&bucket_total,
        (void*)&bucket_off, (void*)&offsets, (void*)&binned,
        (void*)&sorted_col, (void*)&feat_bf,
        (void*)&n_nodes, (void*)&n_edges, (void*)&nb, (void*)&ntiles
    };
    hipLaunchCooperativeKernel((const void*)preprocess_coop,
                               dim3(grid), dim3(256), args, 0, stream);

    {
        long long total = (long long)n_nodes * 64;  // one wave per row
        int block = 256;
        int agrid = (int)((total + block - 1) / block);
        aggregate_kernel<<<agrid, block, 0, stream>>>(feat, feat_bf, offsets, sorted_col,
                                                      out, n_nodes);
    }
}

// Round 9
// 178.275 us; speedup vs baseline: 2.5262x; 2.5262x over previous
//
#include <hip/hip_runtime.h>

// N=100000 nodes, E=1600000 edges, D=64.
#define D_FEAT 64
#define E_BLK 2048           // edges per hist/partition tile -> ntiles = 782
#define MAXB 512             // max buckets (nb = ceil(N/256) = 391)

// Edge packing: (local_row << 24) | col   (col < 2^24, local_row < 256)
// hist_t layout:     [bucket * ntiles + tile]   (contiguous per bucket, for bases)
// base_local layout: [tile * MAXB + bucket]     (contiguous per tile, for partition)

__device__ inline unsigned short f2bf(float f) {
    unsigned u = __float_as_uint(f);
    u += 0x7FFFu + ((u >> 16) & 1u);   // RNE
    return (unsigned short)(u >> 16);
}
__device__ inline float bf2f(unsigned short u) {
    return __uint_as_float(((unsigned)u) << 16);
}

// ---------------- K1: per-tile bucket histogram (+ optional bf16 conv) -----
// Blocks [0, ntiles): histogram. Blocks [ntiles, ...): fp32->bf16 convert.
__global__ __launch_bounds__(256)
void hist_conv_kernel(const int* __restrict__ row, int* __restrict__ hist_t,
                      int n_edges, int nb, int ntiles,
                      const float* __restrict__ feat, unsigned short* __restrict__ feat_bf,
                      int n4) {
    int gb = blockIdx.x;
    int t = threadIdx.x;
    if (gb < ntiles) {
        __shared__ int h[MAXB];
        for (int i = t; i < MAXB; i += 256) h[i] = 0;
        __syncthreads();
        int e0 = gb * E_BLK, e1 = min(e0 + E_BLK, n_edges);
        for (int e = e0 + t; e < e1; e += 256)
            atomicAdd(&h[row[e] >> 8], 1);
        __syncthreads();
        for (int i = t; i < nb; i += 256)
            hist_t[(size_t)i * ntiles + gb] = h[i];
    } else {
        int i = (gb - ntiles) * 256 + t;
        if (i < n4) {
            float4 f = reinterpret_cast<const float4*>(feat)[i];
            ushort4 u;
            u.x = f2bf(f.x); u.y = f2bf(f.y); u.z = f2bf(f.z); u.w = f2bf(f.w);
            reinterpret_cast<ushort4*>(feat_bf)[i] = u;
        }
    }
}

// Standalone converter (fallback schedule when ws is tight; runs after csr).
__global__ __launch_bounds__(256)
void tobf16_kernel(const float* __restrict__ feat, unsigned short* __restrict__ feat_bf,
                   int n4) {
    int i = blockIdx.x * 256 + threadIdx.x;
    if (i >= n4) return;
    float4 f = reinterpret_cast<const float4*>(feat)[i];
    ushort4 u;
    u.x = f2bf(f.x); u.y = f2bf(f.y); u.z = f2bf(f.z); u.w = f2bf(f.w);
    reinterpret_cast<ushort4*>(feat_bf)[i] = u;
}

// ---------------- K2: per-bucket scan over tiles -> bases + totals ---------
__global__ __launch_bounds__(256)
void bases_kernel(const int* __restrict__ hist_t, int* __restrict__ base_local,
                  int* __restrict__ bucket_total, int ntiles) {
    __shared__ int s[256];
    int b = blockIdx.x;
    int t = threadIdx.x;
    const int* hp = hist_t + (size_t)b * ntiles;
    int v[4];
    int sum = 0;
    #pragma unroll
    for (int k = 0; k < 4; ++k) {
        int j = t * 4 + k;
        v[k] = (j < ntiles) ? hp[j] : 0;
        sum += v[k];
    }
    s[t] = sum;
    __syncthreads();
    for (int o = 1; o < 256; o <<= 1) {
        int x = (t >= o) ? s[t - o] : 0;
        __syncthreads();
        s[t] += x;
        __syncthreads();
    }
    int run = s[t] - sum;
    if (t == 255) bucket_total[b] = s[255];
    #pragma unroll
    for (int k = 0; k < 4; ++k) {
        int j = t * 4 + k;
        if (j < ntiles) base_local[(size_t)j * MAXB + b] = run;
        run += v[k];
    }
}

// ---------------- K3: partition (in-block bucket_off scan, LDS cursors) ----
__global__ __launch_bounds__(256)
void partition_kernel(const int* __restrict__ row, const int* __restrict__ col,
                      const int* __restrict__ bucket_total,
                      const int* __restrict__ base_local,
                      int* __restrict__ binned, int n_edges, int nb) {
    __shared__ int cur[MAXB];   // becomes bucket_off + tile base
    __shared__ int s[256];
    int t = threadIdx.x;
    int gb = blockIdx.x;
    // in-block exclusive scan of bucket_total[0..nb) -> cur
    int j0 = 2 * t, j1 = 2 * t + 1;
    int v0 = (j0 < nb) ? bucket_total[j0] : 0;
    int v1 = (j1 < nb) ? bucket_total[j1] : 0;
    int ps = v0 + v1;
    s[t] = ps;
    __syncthreads();
    for (int o = 1; o < 256; o <<= 1) {
        int x = (t >= o) ? s[t - o] : 0;
        __syncthreads();
        s[t] += x;
        __syncthreads();
    }
    int excl = s[t] - ps;
    cur[j0] = excl;
    cur[j1] = excl + v0;
    __syncthreads();
    const int* bl = base_local + (size_t)gb * MAXB;
    for (int i = t; i < nb; i += 256) cur[i] += bl[i];
    __syncthreads();
    int e0 = gb * E_BLK, e1 = min(e0 + E_BLK, n_edges);
    for (int e = e0 + t; e < e1; e += 256) {
        int r = row[e];
        int pos = atomicAdd(&cur[r >> 8], 1);
        binned[pos] = ((r & 255) << 24) | col[e];
    }
}

// ---------------- K4: per-bucket exact CSR (in-block start reduction) ------
__global__ __launch_bounds__(256)
void csr_kernel(const int* __restrict__ binned, const int* __restrict__ bucket_total,
                int* __restrict__ offsets, int* __restrict__ sorted_col,
                int n_nodes, int n_edges, int nb) {
    __shared__ int smem[1024];   // cnt[0..256) sc[256..512) cur[512..768) red[768..1024)
    int* cnt = smem;
    int* sc  = smem + 256;
    int* cur = smem + 512;
    int* red = smem + 768;
    int b = blockIdx.x;
    int t = threadIdx.x;
    // start = sum(bucket_total[0..b))
    int partial = 0;
    for (int j = t; j < b; j += 256) partial += bucket_total[j];
    red[t] = partial;
    __syncthreads();
    for (int o = 128; o > 0; o >>= 1) {
        if (t < o) red[t] += red[t + o];
        __syncthreads();
    }
    int start = red[0];
    int end = start + bucket_total[b];

    int r0 = b << 8;
    cnt[t] = 0;
    __syncthreads();
    for (int i = start + t; i < end; i += 256)
        atomicAdd(&cnt[((unsigned)binned[i]) >> 24], 1);
    __syncthreads();
    int v = cnt[t];
    sc[t] = v;
    __syncthreads();
    for (int o = 1; o < 256; o <<= 1) {
        int x = (t >= o) ? sc[t - o] : 0;
        __syncthreads();
        sc[t] += x;
        __syncthreads();
    }
    int excl = sc[t] - v;
    cur[t] = excl;
    int r = r0 + t;
    if (r < n_nodes) offsets[r] = start + excl;
    if (b == 0 && t == 0) offsets[n_nodes] = n_edges;
    __syncthreads();
    for (int i = start + t; i < end; i += 256) {
        int pk = binned[i];
        int lr = ((unsigned)pk) >> 24;
        int pos = start + atomicAdd(&cur[lr], 1);
        sorted_col[pos] = pk & 0xFFFFFF;
    }
}

// ---------------- K5: one wave per row; bf16 gather (unchanged, 50 us) -----
__global__ __launch_bounds__(256)
void aggregate_kernel(const float* __restrict__ feat,
                      const unsigned short* __restrict__ feat_bf,
                      const int* __restrict__ offsets,
                      const int* __restrict__ sorted_col,
                      float* __restrict__ out, int n_nodes) {
    int wave = (blockIdx.x * blockDim.x + threadIdx.x) >> 6;
    int lane = threadIdx.x & 63;
    if (wave >= n_nodes) return;
    int start = offsets[wave];
    int end = offsets[wave + 1];
    int deg = end - start;
    int q = lane >> 4;
    int sub = lane & 15;

    float4 acc0 = make_float4(0.f, 0.f, 0.f, 0.f);
    float4 acc1 = make_float4(0.f, 0.f, 0.f, 0.f);

    for (int base = 0; base < deg; base += 64) {
        int idx = base + lane;
        int colv = (idx < deg) ? sorted_col[start + idx] : 0;
        int m = min(64, deg - base);
        for (int i = 0; i < m; i += 8) {
            int j0 = i + q;
            int j1 = i + 4 + q;
            int c0 = __shfl(colv, j0, 64);
            int c1 = __shfl(colv, j1, 64);
            if (j0 < m) {
                ushort4 v = *reinterpret_cast<const ushort4*>(
                    feat_bf + (size_t)c0 * D_FEAT + sub * 4);
                acc0.x += bf2f(v.x); acc0.y += bf2f(v.y);
                acc0.z += bf2f(v.z); acc0.w += bf2f(v.w);
            }
            if (j1 < m) {
                ushort4 v = *reinterpret_cast<const ushort4*>(
                    feat_bf + (size_t)c1 * D_FEAT + sub * 4);
                acc1.x += bf2f(v.x); acc1.y += bf2f(v.y);
                acc1.z += bf2f(v.z); acc1.w += bf2f(v.w);
            }
        }
    }
    acc0.x += acc1.x; acc0.y += acc1.y; acc0.z += acc1.z; acc0.w += acc1.w;
    acc0.x += __shfl_xor(acc0.x, 16, 64);
    acc0.y += __shfl_xor(acc0.y, 16, 64);
    acc0.z += __shfl_xor(acc0.z, 16, 64);
    acc0.w += __shfl_xor(acc0.w, 16, 64);
    acc0.x += __shfl_xor(acc0.x, 32, 64);
    acc0.y += __shfl_xor(acc0.y, 32, 64);
    acc0.z += __shfl_xor(acc0.z, 32, 64);
    acc0.w += __shfl_xor(acc0.w, 32, 64);
    if (q == 0) {
        float inv = 1.0f / fmaxf((float)deg, 1.0f);
        size_t off = (size_t)wave * D_FEAT + sub * 4;
        const float4 f = *reinterpret_cast<const float4*>(feat + off);
        float4 o;
        o.x = f.x + acc0.x * inv;
        o.y = f.y + acc0.y * inv;
        o.z = f.z + acc0.z * inv;
        o.w = f.w + acc0.w * inv;
        *reinterpret_cast<float4*>(out + off) = o;
    }
}

extern "C" void kernel_launch(void* const* d_in, const int* in_sizes, int n_in,
                              void* d_out, int out_size, void* d_ws, size_t ws_size,
                              hipStream_t stream) {
    const float* feat = (const float*)d_in[0];
    const int* row = (const int*)d_in[1];
    const int* col = (const int*)d_in[2];
    float* out = (float*)d_out;

    const int n_nodes = in_sizes[0] / D_FEAT;
    const int n_edges = in_sizes[1];
    const int nb = (n_nodes + 255) >> 8;                  // 391
    const int ntiles = (n_edges + E_BLK - 1) / E_BLK;     // 782
    const int n4 = n_nodes * D_FEAT / 4;                  // 1.6M float4s

    char* ws = (char*)d_ws;
    size_t bf_bytes     = (size_t)n_nodes * D_FEAT * 2;   // 12.8 MB
    size_t hist_bytes   = (size_t)nb * ntiles * 4;        // 1.22 MB
    size_t base_bytes   = (size_t)ntiles * MAXB * 4;      // 1.6 MB
    size_t binned_bytes = (size_t)n_edges * 4;            // 6.4 MB
    size_t tail_bytes   = (size_t)n_edges * 4             // sorted_col
                        + (size_t)(n_nodes + 1) * 4       // offsets
                        + (size_t)nb * 4 + 64;            // bucket_total + pad

    size_t fat_need = bf_bytes + hist_bytes + base_bytes + binned_bytes + tail_bytes + 64;
    bool fat = (ws_size >= fat_need);

    unsigned short* feat_bf;
    int *binned, *hist_t, *base_local, *sorted_col, *offsets, *bucket_total;
    if (fat) {
        // Disjoint layout: conversion can run first (fused into K1).
        size_t p = 0;
        feat_bf    = (unsigned short*)(ws + p); p += (bf_bytes + 15) & ~(size_t)15;
        binned     = (int*)(ws + p); p += binned_bytes;
        hist_t     = (int*)(ws + p); p += hist_bytes;
        base_local = (int*)(ws + p); p += base_bytes;
        sorted_col = (int*)(ws + p); p += (size_t)n_edges * 4;
        offsets    = (int*)(ws + p); p += (size_t)(n_nodes + 1) * 4;
        bucket_total = (int*)(ws + p);
    } else {
        // Overlay layout (R7-proven): feat_bf shares {binned,hist_t,base_local};
        // conversion must run after csr.
        size_t sort_bytes = binned_bytes + hist_bytes + base_bytes;
        size_t OV = (sort_bytes > bf_bytes ? sort_bytes : bf_bytes);
        OV = (OV + 15) & ~(size_t)15;
        feat_bf    = (unsigned short*)ws;
        binned     = (int*)ws;
        hist_t     = (int*)(ws + binned_bytes);
        base_local = (int*)(ws + binned_bytes + hist_bytes);
        size_t p = OV;
        sorted_col = (int*)(ws + p); p += (size_t)n_edges * 4;
        offsets    = (int*)(ws + p); p += (size_t)(n_nodes + 1) * 4;
        bucket_total = (int*)(ws + p);
    }

    {
        int conv_blocks = fat ? (n4 + 255) / 256 : 0;
        hist_conv_kernel<<<ntiles + conv_blocks, 256, 0, stream>>>(
            row, hist_t, n_edges, nb, ntiles, feat, feat_bf, n4);
    }
    bases_kernel<<<nb, 256, 0, stream>>>(hist_t, base_local, bucket_total, ntiles);
    partition_kernel<<<ntiles, 256, 0, stream>>>(row, col, bucket_total, base_local,
                                                 binned, n_edges, nb);
    csr_kernel<<<nb, 256, 0, stream>>>(binned, bucket_total, offsets, sorted_col,
                                       n_nodes, n_edges, nb);
    if (!fat) {
        tobf16_kernel<<<(n4 + 255) / 256, 256, 0, stream>>>(feat, feat_bf, n4);
    }
    {
        long long total = (long long)n_nodes * 64;  // one wave per row
        int block = 256;
        int agrid = (int)((total + block - 1) / block);
        aggregate_kernel<<<agrid, block, 0, stream>>>(feat, feat_bf, offsets, sorted_col,
                                                      out, n_nodes);
    }
}

// Round 10
// 171.082 us; speedup vs baseline: 2.6324x; 1.0420x over previous
//
#include <hip/hip_runtime.h>

// N=100000 nodes, E=1600000 edges, D=64.
#define D_FEAT 64
#define E_BLK 2048           // edges per hist/partition tile -> ntiles = 782
#define MAXB 512             // max buckets (nb = ceil(N/256) = 391)

// Edge packing: (local_row << 24) | col   (col < 2^24, local_row < 256)
// hist_t layout:     [bucket * ntiles + tile]
// base_local layout: [tile * MAXB + bucket]

__device__ inline unsigned short f2bf(float f) {
    unsigned u = __float_as_uint(f);
    u += 0x7FFFu + ((u >> 16) & 1u);   // RNE
    return (unsigned short)(u >> 16);
}
__device__ inline float bf_lo(unsigned u) { return __uint_as_float(u << 16); }
__device__ inline float bf_hi(unsigned u) { return __uint_as_float(u & 0xFFFF0000u); }

// ---------------- K1: per-tile bucket histogram (+ optional bf16 conv) -----
__global__ __launch_bounds__(256)
void hist_conv_kernel(const int* __restrict__ row, int* __restrict__ hist_t,
                      int n_edges, int nb, int ntiles,
                      const float* __restrict__ feat, unsigned short* __restrict__ feat_bf,
                      int n4) {
    int gb = blockIdx.x;
    int t = threadIdx.x;
    if (gb < ntiles) {
        __shared__ int h[MAXB];
        for (int i = t; i < MAXB; i += 256) h[i] = 0;
        __syncthreads();
        int e0 = gb * E_BLK, e1 = min(e0 + E_BLK, n_edges);
        for (int e = e0 + t; e < e1; e += 256)
            atomicAdd(&h[row[e] >> 8], 1);
        __syncthreads();
        for (int i = t; i < nb; i += 256)
            hist_t[(size_t)i * ntiles + gb] = h[i];
    } else {
        int i = (gb - ntiles) * 256 + t;
        if (i < n4) {
            float4 f = reinterpret_cast<const float4*>(feat)[i];
            ushort4 u;
            u.x = f2bf(f.x); u.y = f2bf(f.y); u.z = f2bf(f.z); u.w = f2bf(f.w);
            reinterpret_cast<ushort4*>(feat_bf)[i] = u;
        }
    }
}

__global__ __launch_bounds__(256)
void tobf16_kernel(const float* __restrict__ feat, unsigned short* __restrict__ feat_bf,
                   int n4) {
    int i = blockIdx.x * 256 + threadIdx.x;
    if (i >= n4) return;
    float4 f = reinterpret_cast<const float4*>(feat)[i];
    ushort4 u;
    u.x = f2bf(f.x); u.y = f2bf(f.y); u.z = f2bf(f.z); u.w = f2bf(f.w);
    reinterpret_cast<ushort4*>(feat_bf)[i] = u;
}

// ---------------- K2: per-bucket scan over tiles -> bases + totals ---------
__global__ __launch_bounds__(256)
void bases_kernel(const int* __restrict__ hist_t, int* __restrict__ base_local,
                  int* __restrict__ bucket_total, int ntiles) {
    __shared__ int s[256];
    int b = blockIdx.x;
    int t = threadIdx.x;
    const int* hp = hist_t + (size_t)b * ntiles;
    int v[4];
    int sum = 0;
    #pragma unroll
    for (int k = 0; k < 4; ++k) {
        int j = t * 4 + k;
        v[k] = (j < ntiles) ? hp[j] : 0;
        sum += v[k];
    }
    s[t] = sum;
    __syncthreads();
    for (int o = 1; o < 256; o <<= 1) {
        int x = (t >= o) ? s[t - o] : 0;
        __syncthreads();
        s[t] += x;
        __syncthreads();
    }
    int run = s[t] - sum;
    if (t == 255) bucket_total[b] = s[255];
    #pragma unroll
    for (int k = 0; k < 4; ++k) {
        int j = t * 4 + k;
        if (j < ntiles) base_local[(size_t)j * MAXB + b] = run;
        run += v[k];
    }
}

// ---------------- K3: partition (in-block bucket_off scan, LDS cursors) ----
__global__ __launch_bounds__(256)
void partition_kernel(const int* __restrict__ row, const int* __restrict__ col,
                      const int* __restrict__ bucket_total,
                      const int* __restrict__ base_local,
                      int* __restrict__ binned, int n_edges, int nb) {
    __shared__ int cur[MAXB];
    __shared__ int s[256];
    int t = threadIdx.x;
    int gb = blockIdx.x;
    int j0 = 2 * t, j1 = 2 * t + 1;
    int v0 = (j0 < nb) ? bucket_total[j0] : 0;
    int v1 = (j1 < nb) ? bucket_total[j1] : 0;
    int ps = v0 + v1;
    s[t] = ps;
    __syncthreads();
    for (int o = 1; o < 256; o <<= 1) {
        int x = (t >= o) ? s[t - o] : 0;
        __syncthreads();
        s[t] += x;
        __syncthreads();
    }
    int excl = s[t] - ps;
    cur[j0] = excl;
    cur[j1] = excl + v0;
    __syncthreads();
    const int* bl = base_local + (size_t)gb * MAXB;
    for (int i = t; i < nb; i += 256) cur[i] += bl[i];
    __syncthreads();
    int e0 = gb * E_BLK, e1 = min(e0 + E_BLK, n_edges);
    for (int e = e0 + t; e < e1; e += 256) {
        int r = row[e];
        int pos = atomicAdd(&cur[r >> 8], 1);
        binned[pos] = ((r & 255) << 24) | col[e];
    }
}

// ---------------- K4: per-bucket exact CSR (in-block start reduction) ------
__global__ __launch_bounds__(256)
void csr_kernel(const int* __restrict__ binned, const int* __restrict__ bucket_total,
                int* __restrict__ offsets, int* __restrict__ sorted_col,
                int n_nodes, int n_edges, int nb) {
    __shared__ int smem[1024];
    int* cnt = smem;
    int* sc  = smem + 256;
    int* cur = smem + 512;
    int* red = smem + 768;
    int b = blockIdx.x;
    int t = threadIdx.x;
    int partial = 0;
    for (int j = t; j < b; j += 256) partial += bucket_total[j];
    red[t] = partial;
    __syncthreads();
    for (int o = 128; o > 0; o >>= 1) {
        if (t < o) red[t] += red[t + o];
        __syncthreads();
    }
    int start = red[0];
    int end = start + bucket_total[b];

    int r0 = b << 8;
    cnt[t] = 0;
    __syncthreads();
    for (int i = start + t; i < end; i += 256)
        atomicAdd(&cnt[((unsigned)binned[i]) >> 24], 1);
    __syncthreads();
    int v = cnt[t];
    sc[t] = v;
    __syncthreads();
    for (int o = 1; o < 256; o <<= 1) {
        int x = (t >= o) ? sc[t - o] : 0;
        __syncthreads();
        sc[t] += x;
        __syncthreads();
    }
    int excl = sc[t] - v;
    cur[t] = excl;
    int r = r0 + t;
    if (r < n_nodes) offsets[r] = start + excl;
    if (b == 0 && t == 0) offsets[n_nodes] = n_edges;
    __syncthreads();
    for (int i = start + t; i < end; i += 256) {
        int pk = binned[i];
        int lr = ((unsigned)pk) >> 24;
        int pos = start + atomicAdd(&cur[lr], 1);
        sorted_col[pos] = pk & 0xFFFFFF;
    }
}

// ---------------- K5: one wave per row; 8 lanes/edge, dwordx4 gather -------
__global__ __launch_bounds__(256)
void aggregate_kernel(const float* __restrict__ feat,
                      const unsigned short* __restrict__ feat_bf,
                      const int* __restrict__ offsets,
                      const int* __restrict__ sorted_col,
                      float* __restrict__ out, int n_nodes) {
    int wave = (blockIdx.x * blockDim.x + threadIdx.x) >> 6;
    int lane = threadIdx.x & 63;
    if (wave >= n_nodes) return;
    int start = offsets[wave];
    int end = offsets[wave + 1];
    int deg = end - start;
    int q = lane >> 3;      // 8 edge-groups
    int sub = lane & 7;     // 16B (8 bf16) slot within the 128B row

    float acc0[8], acc1[8];
    #pragma unroll
    for (int k = 0; k < 8; ++k) { acc0[k] = 0.f; acc1[k] = 0.f; }

    for (int base = 0; base < deg; base += 64) {
        int idx = base + lane;
        int colv = (idx < deg) ? sorted_col[start + idx] : 0;  // 1 coalesced load / 64 edges
        int m = min(64, deg - base);
        for (int i = 0; i < m; i += 16) {
            int j0 = i + q;
            int j1 = i + 8 + q;
            int c0 = __shfl(colv, j0, 64);
            int c1 = __shfl(colv, j1, 64);
            if (j0 < m) {
                uint4 d = *reinterpret_cast<const uint4*>(
                    feat_bf + (size_t)c0 * D_FEAT + sub * 8);
                acc0[0] += bf_lo(d.x); acc0[1] += bf_hi(d.x);
                acc0[2] += bf_lo(d.y); acc0[3] += bf_hi(d.y);
                acc0[4] += bf_lo(d.z); acc0[5] += bf_hi(d.z);
                acc0[6] += bf_lo(d.w); acc0[7] += bf_hi(d.w);
            }
            if (j1 < m) {
                uint4 d = *reinterpret_cast<const uint4*>(
                    feat_bf + (size_t)c1 * D_FEAT + sub * 8);
                acc1[0] += bf_lo(d.x); acc1[1] += bf_hi(d.x);
                acc1[2] += bf_lo(d.y); acc1[3] += bf_hi(d.y);
                acc1[4] += bf_lo(d.z); acc1[5] += bf_hi(d.z);
                acc1[6] += bf_lo(d.w); acc1[7] += bf_hi(d.w);
            }
        }
    }
    #pragma unroll
    for (int k = 0; k < 8; ++k) acc0[k] += acc1[k];
    // fold the 8 edge-groups: lanes with same sub differ in bits 3..5
    #pragma unroll
    for (int k = 0; k < 8; ++k) {
        acc0[k] += __shfl_xor(acc0[k], 8, 64);
        acc0[k] += __shfl_xor(acc0[k], 16, 64);
        acc0[k] += __shfl_xor(acc0[k], 32, 64);
    }
    if (q == 0) {
        float inv = 1.0f / fmaxf((float)deg, 1.0f);
        size_t off = (size_t)wave * D_FEAT + sub * 8;
        const float4 f0 = *reinterpret_cast<const float4*>(feat + off);
        const float4 f1 = *reinterpret_cast<const float4*>(feat + off + 4);
        float4 o0, o1;
        o0.x = f0.x + acc0[0] * inv;
        o0.y = f0.y + acc0[1] * inv;
        o0.z = f0.z + acc0[2] * inv;
        o0.w = f0.w + acc0[3] * inv;
        o1.x = f1.x + acc0[4] * inv;
        o1.y = f1.y + acc0[5] * inv;
        o1.z = f1.z + acc0[6] * inv;
        o1.w = f1.w + acc0[7] * inv;
        *reinterpret_cast<float4*>(out + off) = o0;
        *reinterpret_cast<float4*>(out + off + 4) = o1;
    }
}

extern "C" void kernel_launch(void* const* d_in, const int* in_sizes, int n_in,
                              void* d_out, int out_size, void* d_ws, size_t ws_size,
                              hipStream_t stream) {
    const float* feat = (const float*)d_in[0];
    const int* row = (const int*)d_in[1];
    const int* col = (const int*)d_in[2];
    float* out = (float*)d_out;

    const int n_nodes = in_sizes[0] / D_FEAT;
    const int n_edges = in_sizes[1];
    const int nb = (n_nodes + 255) >> 8;                  // 391
    const int ntiles = (n_edges + E_BLK - 1) / E_BLK;     // 782
    const int n4 = n_nodes * D_FEAT / 4;                  // 1.6M float4s

    char* ws = (char*)d_ws;
    size_t bf_bytes     = (size_t)n_nodes * D_FEAT * 2;   // 12.8 MB
    size_t hist_bytes   = (size_t)nb * ntiles * 4;        // 1.22 MB
    size_t base_bytes   = (size_t)ntiles * MAXB * 4;      // 1.6 MB
    size_t binned_bytes = (size_t)n_edges * 4;            // 6.4 MB
    size_t tail_bytes   = (size_t)n_edges * 4
                        + (size_t)(n_nodes + 1) * 4
                        + (size_t)nb * 4 + 64;

    size_t fat_need = bf_bytes + hist_bytes + base_bytes + binned_bytes + tail_bytes + 64;
    bool fat = (ws_size >= fat_need);

    unsigned short* feat_bf;
    int *binned, *hist_t, *base_local, *sorted_col, *offsets, *bucket_total;
    if (fat) {
        size_t p = 0;
        feat_bf    = (unsigned short*)(ws + p); p += (bf_bytes + 15) & ~(size_t)15;
        binned     = (int*)(ws + p); p += binned_bytes;
        hist_t     = (int*)(ws + p); p += hist_bytes;
        base_local = (int*)(ws + p); p += base_bytes;
        sorted_col = (int*)(ws + p); p += (size_t)n_edges * 4;
        offsets    = (int*)(ws + p); p += (size_t)(n_nodes + 1) * 4;
        bucket_total = (int*)(ws + p);
    } else {
        size_t sort_bytes = binned_bytes + hist_bytes + base_bytes;
        size_t OV = (sort_bytes > bf_bytes ? sort_bytes : bf_bytes);
        OV = (OV + 15) & ~(size_t)15;
        feat_bf    = (unsigned short*)ws;
        binned     = (int*)ws;
        hist_t     = (int*)(ws + binned_bytes);
        base_local = (int*)(ws + binned_bytes + hist_bytes);
        size_t p = OV;
        sorted_col = (int*)(ws + p); p += (size_t)n_edges * 4;
        offsets    = (int*)(ws + p); p += (size_t)(n_nodes + 1) * 4;
        bucket_total = (int*)(ws + p);
    }

    {
        int conv_blocks = fat ? (n4 + 255) / 256 : 0;
        hist_conv_kernel<<<ntiles + conv_blocks, 256, 0, stream>>>(
            row, hist_t, n_edges, nb, ntiles, feat, feat_bf, n4);
    }
    bases_kernel<<<nb, 256, 0, stream>>>(hist_t, base_local, bucket_total, ntiles);
    partition_kernel<<<ntiles, 256, 0, stream>>>(row, col, bucket_total, base_local,
                                                 binned, n_edges, nb);
    csr_kernel<<<nb, 256, 0, stream>>>(binned, bucket_total, offsets, sorted_col,
                                       n_nodes, n_edges, nb);
    if (!fat) {
        tobf16_kernel<<<(n4 + 255) / 256, 256, 0, stream>>>(feat, feat_bf, n4);
    }
    {
        long long total = (long long)n_nodes * 64;  // one wave per row
        int block = 256;
        int agrid = (int)((total + block - 1) / block);
        aggregate_kernel<<<agrid, block, 0, stream>>>(feat, feat_bf, offsets, sorted_col,
                                                      out, n_nodes);
    }
}